// Round 1
// baseline (341.321 us; speedup 1.0000x reference)
//
#include <hip/hip_runtime.h>
#include <hip/hip_bf16.h>

#define D 128
#define NH 256
#define K1 384
#define BM 64
#define E_TOTAL 320000
#define NNODES 10000

typedef __attribute__((ext_vector_type(8))) short bf16x8;
typedef __attribute__((ext_vector_type(4))) float f32x4;

__device__ __forceinline__ unsigned short f2b(float f) {
  unsigned int u = __builtin_bit_cast(unsigned int, f);
  u += 0x7fffu + ((u >> 16) & 1u);   // round-to-nearest-even
  return (unsigned short)(u >> 16);
}

// nodes fp32 -> bf16 table (makes the per-edge gathers 2B/elem and L2-hot)
__global__ void cast_nodes_kernel(const float* __restrict__ nodes,
                                  ushort* __restrict__ out) {
  int i = (blockIdx.x * 256 + threadIdx.x) * 4;
  float4 v = *(const float4*)(nodes + i);
  ushort4 b;
  b.x = f2b(v.x); b.y = f2b(v.y); b.z = f2b(v.z); b.w = f2b(v.w);
  *(ushort4*)(out + i) = b;
}

// transpose-cast: in fp32 [K][N] -> out bf16 [N][K] (B-fragments contiguous in K)
__global__ void transpose_cast_kernel(const float* __restrict__ in,
                                      ushort* __restrict__ out,
                                      int K, int N) {
  __shared__ float tile[64][65];
  int kb = blockIdx.x * 64;
  int nb = blockIdx.y * 64;
  int t = threadIdx.x;     // 256
  int c = t & 63;
  int r0 = t >> 6;
  #pragma unroll
  for (int i = 0; i < 16; ++i) {
    int r = r0 + i * 4;
    tile[r][c] = in[(size_t)(kb + r) * N + nb + c];
  }
  __syncthreads();
  #pragma unroll
  for (int i = 0; i < 16; ++i) {
    int rr = r0 + i * 4;
    out[(size_t)(nb + rr) * K + kb + c] = f2b(tile[c][rr]);
  }
}

// cvec[n] = b1[n] + sum_k globals[k] * W1[384+k][n]  (the constant globals slice)
__global__ void cvec_kernel(const float* __restrict__ W1,
                            const float* __restrict__ b1,
                            const float* __restrict__ g,
                            float* __restrict__ cvec) {
  int n = threadIdx.x;  // 256
  float acc = b1[n];
  for (int k = 0; k < D; ++k)
    acc += g[k] * W1[(size_t)(K1 + k) * NH + n];
  cvec[n] = acc;
}

__global__ __launch_bounds__(512, 4) void fused_kernel(
    const float* __restrict__ edges,
    const ushort* __restrict__ nodes_b,
    const int* __restrict__ receivers,
    const int* __restrict__ senders,
    const ushort* __restrict__ W1bT,   // [256][384] bf16
    const float* __restrict__ cvec,    // [256]
    const ushort* __restrict__ W2bT,   // [128][256] bf16
    const float* __restrict__ b2,      // [128]
    float* __restrict__ out) {
  // X tile: 64 rows x 384 bf16 (768 B/row), XOR-swizzled: byte ^= (row&7)<<4
  __shared__ char Xs[BM * 768];
  // H tile: 64 rows x 256 bf16 (512 B/row), same swizzle
  __shared__ char Hs[BM * 512];

  const int ebase = blockIdx.x * BM;
  const int tid = threadIdx.x;

  // ---- stage edges (fp32 -> bf16), rows 64 x 128 cols
  #pragma unroll
  for (int it = 0; it < 4; ++it) {
    int ch = tid + it * 512;          // 2048 chunks of 4 floats
    int r = ch >> 5;
    int c = (ch & 31) << 2;
    float4 v = *(const float4*)(edges + (size_t)(ebase + r) * D + c);
    ushort4 b;
    b.x = f2b(v.x); b.y = f2b(v.y); b.z = f2b(v.z); b.w = f2b(v.w);
    *(ushort4*)(Xs + r * 768 + ((c * 2) ^ ((r & 7) << 4))) = b;
  }
  // ---- stage recv / send gathers (bf16 16B chunks)
  #pragma unroll
  for (int p = 0; p < 2; ++p) {
    const int* __restrict__ idxp = p ? senders : receivers;
    #pragma unroll
    for (int it = 0; it < 2; ++it) {
      int ch = tid + it * 512;        // 1024 chunks of 8 bf16
      int r = ch >> 4;
      int c = (ch & 15) << 3;
      int nd = idxp[ebase + r];
      uint4 v = *(const uint4*)(nodes_b + (size_t)nd * D + c);
      int cc = (p + 1) * D + c;
      *(uint4*)(Xs + r * 768 + ((cc * 2) ^ ((r & 7) << 4))) = v;
    }
  }
  __syncthreads();

  const int lane = tid & 63;
  const int wave = tid >> 6;
  const int wm = wave >> 2;   // 0..1 : 32-row group
  const int wn = wave & 3;    // 0..3 : 64-col group (GEMM1) / 32-col (GEMM2)
  const int lr = lane & 15;
  const int kg = lane >> 4;   // 0..3

  // ---- GEMM1: [64x384] @ [384x256]
  f32x4 acc[2][4] = {};
  #pragma unroll
  for (int ks = 0; ks < 12; ++ks) {
    const int k0 = ks * 32 + kg * 8;
    bf16x8 a[2], b[4];
    #pragma unroll
    for (int m = 0; m < 2; ++m) {
      int row = wm * 32 + m * 16 + lr;
      a[m] = *(const bf16x8*)(Xs + row * 768 + ((k0 * 2) ^ ((row & 7) << 4)));
    }
    #pragma unroll
    for (int n = 0; n < 4; ++n) {
      int col = wn * 64 + n * 16 + lr;
      b[n] = *(const bf16x8*)(W1bT + (size_t)col * K1 + k0);
    }
    #pragma unroll
    for (int m = 0; m < 2; ++m)
      #pragma unroll
      for (int n = 0; n < 4; ++n)
        acc[m][n] = __builtin_amdgcn_mfma_f32_16x16x32_bf16(a[m], b[n], acc[m][n], 0, 0, 0);
  }

  // ---- epilogue 1: + cvec, relu, -> bf16 Hs
  #pragma unroll
  for (int n = 0; n < 4; ++n) {
    int col = wn * 64 + n * 16 + lr;
    float cv = cvec[col];
    #pragma unroll
    for (int m = 0; m < 2; ++m) {
      #pragma unroll
      for (int r = 0; r < 4; ++r) {
        int row = wm * 32 + m * 16 + kg * 4 + r;
        float v = acc[m][n][r] + cv;
        v = v > 0.f ? v : 0.f;
        *(ushort*)(Hs + row * 512 + ((col * 2) ^ ((row & 7) << 4))) = f2b(v);
      }
    }
  }
  __syncthreads();

  // ---- GEMM2: [64x256] @ [256x128]
  f32x4 acc2[2][2] = {};
  #pragma unroll
  for (int ks = 0; ks < 8; ++ks) {
    const int k0 = ks * 32 + kg * 8;
    bf16x8 a[2], b[2];
    #pragma unroll
    for (int m = 0; m < 2; ++m) {
      int row = wm * 32 + m * 16 + lr;
      a[m] = *(const bf16x8*)(Hs + row * 512 + ((k0 * 2) ^ ((row & 7) << 4)));
    }
    #pragma unroll
    for (int n = 0; n < 2; ++n) {
      int col = wn * 32 + n * 16 + lr;
      b[n] = *(const bf16x8*)(W2bT + (size_t)col * NH + k0);
    }
    #pragma unroll
    for (int m = 0; m < 2; ++m)
      #pragma unroll
      for (int n = 0; n < 2; ++n)
        acc2[m][n] = __builtin_amdgcn_mfma_f32_16x16x32_bf16(a[m], b[n], acc2[m][n], 0, 0, 0);
  }

  // ---- epilogue 2: + b2, store fp32
  #pragma unroll
  for (int n = 0; n < 2; ++n) {
    int col = wn * 32 + n * 16 + lr;
    float bias = b2[col];
    #pragma unroll
    for (int m = 0; m < 2; ++m) {
      #pragma unroll
      for (int r = 0; r < 4; ++r) {
        int row = wm * 32 + m * 16 + kg * 4 + r;
        out[(size_t)(ebase + row) * D + col] = acc2[m][n][r] + bias;
      }
    }
  }
}

extern "C" void kernel_launch(void* const* d_in, const int* in_sizes, int n_in,
                              void* d_out, int out_size, void* d_ws, size_t ws_size,
                              hipStream_t stream) {
  const float* edges     = (const float*)d_in[0];
  const float* nodes     = (const float*)d_in[1];
  const float* globals_  = (const float*)d_in[2];
  const int*   receivers = (const int*)d_in[3];
  const int*   senders   = (const int*)d_in[4];
  const float* W1        = (const float*)d_in[5];
  const float* b1        = (const float*)d_in[6];
  const float* W2        = (const float*)d_in[7];
  const float* b2        = (const float*)d_in[8];
  float* out = (float*)d_out;

  char* ws = (char*)d_ws;
  ushort* nodes_b = (ushort*)ws;                                // 2,560,000 B
  ushort* W1bT    = (ushort*)(ws + 2560000);                    //   196,608 B
  ushort* W2bT    = (ushort*)(ws + 2560000 + 196608);           //    65,536 B
  float*  cvec    = (float*)(ws + 2560000 + 196608 + 65536);    //     1,024 B

  hipLaunchKernelGGL(cast_nodes_kernel, dim3(NNODES * D / 1024), dim3(256), 0, stream,
                     nodes, nodes_b);
  hipLaunchKernelGGL(transpose_cast_kernel, dim3(K1 / 64, NH / 64), dim3(256), 0, stream,
                     W1, W1bT, K1, NH);
  hipLaunchKernelGGL(transpose_cast_kernel, dim3(NH / 64, D / 64), dim3(256), 0, stream,
                     W2, W2bT, NH, D);
  hipLaunchKernelGGL(cvec_kernel, dim3(1), dim3(256), 0, stream,
                     W1, b1, globals_, cvec);
  hipLaunchKernelGGL(fused_kernel, dim3(E_TOTAL / BM), dim3(512), 0, stream,
                     edges, nodes_b, receivers, senders, W1bT, cvec, W2bT, b2, out);
}